// Round 1
// baseline (500.597 us; speedup 1.0000x reference)
//
#include <hip/hip_runtime.h>
#include <math.h>

#define NRAYS 8192
#define T 128
#define H 128
#define SHD 16

__device__ __forceinline__ float softplus_f(float x) {
  // jax.nn.softplus = logaddexp(x, 0), stable form
  return fmaxf(x, 0.f) + log1pf(expf(-fabsf(x)));
}

__global__ __launch_bounds__(256) void nerf_render(
    const float* __restrict__ origins, const float* __restrict__ dirs,
    const float* __restrict__ u, const float* __restrict__ W1,
    const float* __restrict__ b1, const float* __restrict__ W2,
    const float* __restrict__ b2, const float* __restrict__ Wd,
    const float* __restrict__ bd, const float* __restrict__ Wc,
    const float* __restrict__ bc, float* __restrict__ out)
{
  const int ray = blockIdx.x;
  const int tid = threadIdx.x;
  const int tx = tid & 15;        // column tile index (hidden dim)
  const int ty = tid >> 4;        // row tile index (sample dim), 0..15
  const int row0 = ty * 8;
  const int col0 = tx * 8;

  __shared__ __align__(16) float As[16][T];   // relu(H1) chunk, k-major
  __shared__ __align__(16) float Bs[16][H];   // W2 chunk
  __shared__ float xs[T][3];
  __shared__ float ts_s[T];
  __shared__ float mask_s[T];
  __shared__ float W1s[3 * H];
  __shared__ float b1s[H];
  __shared__ float b2s[H];
  __shared__ float Wds[H];
  __shared__ float Wcs[(H + SHD) * 3];
  __shared__ float Sred[T][4];                // per-sample: sigma_pre, col_pre[3]
  __shared__ float sc_a[T], sc_b[T];          // scan ping-pong
  __shared__ float wred[4][4];

  // ---- stage weights into LDS ----
  for (int i = tid; i < 3 * H; i += 256) W1s[i] = W1[i];
  for (int i = tid; i < H; i += 256) { b1s[i] = b1[i]; b2s[i] = b2[i]; Wds[i] = Wd[i]; }
  for (int i = tid; i < (H + SHD) * 3; i += 256) Wcs[i] = Wc[i];

  // ---- per-ray setup (redundant across threads; cheap) ----
  const float ox = origins[ray*3+0], oy = origins[ray*3+1], oz = origins[ray*3+2];
  const float dx = dirs[ray*3+0],  dy = dirs[ray*3+1],  dz = dirs[ray*3+2];
  const float ix = 1.f/dx, iy = 1.f/dy, iz = 1.f/dz;
  const float t1x = (-1.f-ox)*ix, t2x = (1.f-ox)*ix;
  const float t1y = (-1.f-oy)*iy, t2y = (1.f-oy)*iy;
  const float t1z = (-1.f-oz)*iz, t2z = (1.f-oz)*iz;
  float tnear = fmaxf(fmaxf(fminf(t1x,t2x), fminf(t1y,t2y)), fminf(t1z,t2z));
  tnear = fmaxf(tnear, 0.f);
  const float tfar = fminf(fminf(fmaxf(t1x,t2x), fmaxf(t1y,t2y)), fmaxf(t1z,t2z));
  const bool  active = tfar > tnear;
  const float tfar_c = fmaxf(tfar, tnear + 1e-3f);
  const float dnorm = sqrtf(dx*dx + dy*dy + dz*dz);
  const float bd0 = bd[0];
  const float bc0 = bc[0], bc1 = bc[1], bc2 = bc[2];

  // ---- spherical harmonics of normalized dir ----
  float ynm[16];
  {
    const float nx = dx/dnorm, ny = dy/dnorm, nz = dz/dnorm;
    const float x2 = nx*nx, y2 = ny*ny, z2 = nz*nz;
    const float xy = nx*ny, yz = ny*nz, xz = nx*nz;
    ynm[0]  = 0.282094791773878f;
    ynm[1]  = -0.48860251190292f*ny;
    ynm[2]  = 0.48860251190292f*nz;
    ynm[3]  = -0.48860251190292f*nx;
    ynm[4]  = 1.0925484305920792f*xy;
    ynm[5]  = -1.0925484305920792f*yz;
    ynm[6]  = 0.94617469575756f*z2 - 0.31539156525252f;
    ynm[7]  = -1.0925484305920792f*xz;
    ynm[8]  = 0.5462742152960396f*(x2-y2);
    ynm[9]  = 0.5900435899266435f*ny*(-3.f*x2+y2);
    ynm[10] = 2.8906114426405538f*xy*nz;
    ynm[11] = 0.4570457994644658f*ny*(1.f-5.f*z2);
    ynm[12] = 0.3731763325901154f*nz*(5.f*z2-3.f);
    ynm[13] = 1.445305721320277f*nz*(x2-y2);   // placeholder, fixed below
    ynm[14] = 1.445305721320277f*nz*(x2-y2);
    ynm[15] = 0.5900435899266435f*nx*(-x2+3.f*y2);
    // correct order: index 13 is the x term, 14 the z(x2-y2) term
    ynm[13] = 0.4570457994644658f*nx*(1.f-5.f*z2);
  }

  // ---- stratified samples ----
  if (tid < T) {
    const float ut = u[ray*T + tid];
    const float frac = ((float)tid + ut) * (1.f/(float)T);
    const float tt = tnear + (tfar_c - tnear) * frac;
    const float px = fmaf(dx, tt, ox);
    const float py = fmaf(dy, tt, oy);
    const float pz = fmaf(dz, tt, oz);
    xs[tid][0] = px; xs[tid][1] = py; xs[tid][2] = pz;
    ts_s[tid] = tt;
    const bool m = (fabsf(px) <= 1.f) && (fabsf(py) <= 1.f) && (fabsf(pz) <= 1.f) && active;
    mask_s[tid] = m ? 1.f : 0.f;
  }
  __syncthreads();

  // ---- fused layer1 + layer2 GEMM: H2pre[t][j] = sum_k relu(H1[t][k]) * W2[k][j] ----
  float acc[8][8];
  #pragma unroll
  for (int r = 0; r < 8; ++r)
    #pragma unroll
    for (int c = 0; c < 8; ++c) acc[r][c] = 0.f;

  for (int kc = 0; kc < 8; ++kc) {
    // stage A chunk: this thread handles k = kc*16+ty, samples t = tx + 16r
    const int k = kc*16 + ty;
    const float w0 = W1s[0*H + k], w1 = W1s[1*H + k], w2 = W1s[2*H + k], bb = b1s[k];
    #pragma unroll
    for (int r = 0; r < 8; ++r) {
      const int t = tx + r*16;
      const float v = fmaf(xs[t][0], w0, fmaf(xs[t][1], w1, fmaf(xs[t][2], w2, bb)));
      As[ty][t] = fmaxf(v, 0.f);
    }
    // stage B chunk: W2 row k, cols tx*8..tx*8+7 (two float4 loads, L2-hot)
    const float4 p0 = ((const float4*)(W2 + k*H + tx*8))[0];
    const float4 p1 = ((const float4*)(W2 + k*H + tx*8))[1];
    ((float4*)&Bs[ty][tx*8])[0] = p0;
    ((float4*)&Bs[ty][tx*8])[1] = p1;
    __syncthreads();

    #pragma unroll
    for (int kk = 0; kk < 16; ++kk) {
      const float4 a0 = ((const float4*)&As[kk][row0])[0];
      const float4 a1 = ((const float4*)&As[kk][row0])[1];
      const float4 q0 = ((const float4*)&Bs[kk][col0])[0];
      const float4 q1 = ((const float4*)&Bs[kk][col0])[1];
      const float av[8] = {a0.x,a0.y,a0.z,a0.w,a1.x,a1.y,a1.z,a1.w};
      const float bv[8] = {q0.x,q0.y,q0.z,q0.w,q1.x,q1.y,q1.z,q1.w};
      #pragma unroll
      for (int r = 0; r < 8; ++r)
        #pragma unroll
        for (int c = 0; c < 8; ++c)
          acc[r][c] = fmaf(av[r], bv[c], acc[r][c]);
    }
    __syncthreads();
  }

  // ---- epilogue partial dots: sigma_pre & color_pre, reduce across 16 col-threads ----
  #pragma unroll
  for (int r = 0; r < 8; ++r) {
    float ps = 0.f, pc0 = 0.f, pc1 = 0.f, pc2 = 0.f;
    #pragma unroll
    for (int c = 0; c < 8; ++c) {
      const int j = col0 + c;
      const float h2 = fmaxf(acc[r][c] + b2s[j], 0.f);
      ps  = fmaf(h2, Wds[j], ps);
      pc0 = fmaf(h2, Wcs[j*3+0], pc0);
      pc1 = fmaf(h2, Wcs[j*3+1], pc1);
      pc2 = fmaf(h2, Wcs[j*3+2], pc2);
    }
    // threads sharing a row are 16 contiguous lanes (tx = lane & 15)
    #pragma unroll
    for (int m = 8; m >= 1; m >>= 1) {
      ps  += __shfl_xor(ps, m);
      pc0 += __shfl_xor(pc0, m);
      pc1 += __shfl_xor(pc1, m);
      pc2 += __shfl_xor(pc2, m);
    }
    if (tx == 0) {
      Sred[row0+r][0] = ps;  Sred[row0+r][1] = pc0;
      Sred[row0+r][2] = pc1; Sred[row0+r][3] = pc2;
    }
  }
  __syncthreads();

  // ---- per-sample activations + transmittance terms ----
  float sd = 0.f, cc0 = 0.f, cc1 = 0.f, cc2 = 0.f;
  if (tid < T) {
    const float spre = Sred[tid][0] + bd0;
    const float sigma = softplus_f(spre) * mask_s[tid];
    float cp0 = Sred[tid][1] + bc0;
    float cp1 = Sred[tid][2] + bc1;
    float cp2 = Sred[tid][3] + bc2;
    #pragma unroll
    for (int s = 0; s < SHD; ++s) {
      cp0 = fmaf(ynm[s], Wcs[(H+s)*3+0], cp0);
      cp1 = fmaf(ynm[s], Wcs[(H+s)*3+1], cp1);
      cp2 = fmaf(ynm[s], Wcs[(H+s)*3+2], cp2);
    }
    const float m = mask_s[tid];
    cc0 = m / (1.f + expf(-cp0));
    cc1 = m / (1.f + expf(-cp1));
    cc2 = m / (1.f + expf(-cp2));
    const float tnext = (tid < T-1) ? ts_s[tid+1] : tfar_c * 10.f;
    const float delta = tnext - ts_s[tid];
    sd = sigma * delta * dnorm;
    sc_a[tid] = sd;
  }
  __syncthreads();

  // ---- inclusive scan of sd (Hillis-Steele, ping-pong) ----
  float* srcp = sc_a; float* dstp = sc_b;
  for (int off = 1; off < T; off <<= 1) {
    float v = 0.f;
    if (tid < T) { v = srcp[tid]; if (tid >= off) v += srcp[tid - off]; }
    __syncthreads();
    if (tid < T) dstp[tid] = v;
    __syncthreads();
    float* tmp = srcp; srcp = dstp; dstp = tmp;
  }

  // ---- weights + weighted color/alpha reduction ----
  float w = 0.f, wc0 = 0.f, wc1 = 0.f, wc2 = 0.f;
  if (tid < T) {
    const float csum = srcp[tid];
    w = expf(sd - csum) - expf(-csum);
    wc0 = w * cc0; wc1 = w * cc1; wc2 = w * cc2;
  }
  #pragma unroll
  for (int m = 32; m >= 1; m >>= 1) {
    w   += __shfl_xor(w, m);
    wc0 += __shfl_xor(wc0, m);
    wc1 += __shfl_xor(wc1, m);
    wc2 += __shfl_xor(wc2, m);
  }
  if ((tid & 63) == 0) {
    wred[tid>>6][0] = w;   wred[tid>>6][1] = wc0;
    wred[tid>>6][2] = wc1; wred[tid>>6][3] = wc2;
  }
  __syncthreads();
  if (tid == 0) {
    float aw = 0.f, c0 = 0.f, c1 = 0.f, c2 = 0.f;
    #pragma unroll
    for (int i = 0; i < 4; ++i) {
      aw += wred[i][0]; c0 += wred[i][1]; c1 += wred[i][2]; c2 += wred[i][3];
    }
    out[ray*4+0] = active ? c0 : 0.f;
    out[ray*4+1] = active ? c1 : 0.f;
    out[ray*4+2] = active ? c2 : 0.f;
    out[ray*4+3] = active ? aw : 0.f;
  }
}

extern "C" void kernel_launch(void* const* d_in, const int* in_sizes, int n_in,
                              void* d_out, int out_size, void* d_ws, size_t ws_size,
                              hipStream_t stream) {
  const float* origins = (const float*)d_in[0];
  const float* dirs    = (const float*)d_in[1];
  const float* u       = (const float*)d_in[2];
  const float* W1      = (const float*)d_in[3];
  const float* b1      = (const float*)d_in[4];
  const float* W2      = (const float*)d_in[5];
  const float* b2      = (const float*)d_in[6];
  const float* Wd      = (const float*)d_in[7];
  const float* bd      = (const float*)d_in[8];
  const float* Wc      = (const float*)d_in[9];
  const float* bc      = (const float*)d_in[10];
  nerf_render<<<NRAYS, 256, 0, stream>>>(origins, dirs, u, W1, b1, W2, b2,
                                         Wd, bd, Wc, bc, (float*)d_out);
}

// Round 2
// 194.511 us; speedup vs baseline: 2.5736x; 2.5736x over previous
//
#include <hip/hip_runtime.h>
#include <math.h>

#define NRAYS 8192
#define T 128
#define H 128
#define SHD 16

using short8 = __attribute__((ext_vector_type(8))) short;
using f32x4  = __attribute__((ext_vector_type(4))) float;

__device__ __forceinline__ float softplus_f(float x) {
  return fmaxf(x, 0.f) + log1pf(expf(-fabsf(x)));
}

// RNE float->bf16 (finite inputs)
__device__ __forceinline__ unsigned short f2bf(float f) {
  unsigned u = __float_as_uint(f);
  return (unsigned short)((u + 0x7fffu + ((u >> 16) & 1u)) >> 16);
}

// ---- preprocess: W2 -> bf16, transposed + XOR-swizzled; pack Wd/Wc ----
// stored index: n*128 + (o ^ (n&7))*8 + j  holds  W2[(o*8+j)*... wait k=o*8+j][n]
__global__ void preprocess(const float* __restrict__ W2, const float* __restrict__ Wd,
                           const float* __restrict__ Wc,
                           unsigned short* __restrict__ w2t, float4* __restrict__ wpack) {
  const int t = blockIdx.x * 256 + threadIdx.x;
  if (t < 16384) {
    const int n = t >> 7, p = t & 127;
    const int o = (p >> 3) ^ (n & 7);      // actual k-octet stored at position p>>3
    const int k = o * 8 + (p & 7);
    w2t[t] = f2bf(W2[k * 128 + n]);
  }
  if (t < 128) wpack[t] = make_float4(Wd[t], Wc[t*3+0], Wc[t*3+1], Wc[t*3+2]);
}

__global__ __launch_bounds__(256) void nerf_render(
    const float* __restrict__ origins, const float* __restrict__ dirs,
    const float* __restrict__ u, const float* __restrict__ W1,
    const float* __restrict__ b1, const float* __restrict__ b2,
    const float* __restrict__ bd, const float* __restrict__ Wc,
    const float* __restrict__ bc, const unsigned short* __restrict__ w2t,
    const float4* __restrict__ wpack, float* __restrict__ out)
{
  const int ray = blockIdx.x;
  const int tid = threadIdx.x;
  const int L = tid & 63;          // lane
  const int w = tid >> 6;          // wave 0..3 -> sample rows [32w, 32w+32)
  const int g = L >> 4;            // quad group 0..3
  const int c = L & 15;            // lane-within-16

  // Bs (16384 bf16, swizzled W2^T) aliases P (128 x 17 float4 partials)
  __shared__ __align__(16) unsigned char BsP[34816];
  __shared__ __align__(16) float4 xs4[T];        // {x,y,z,t} per sample
  __shared__ float mask_s[T];
  __shared__ __align__(16) float W1s[3 * H];     // [c][k]
  __shared__ __align__(16) float b1s[H];
  __shared__ float b2s[H];
  __shared__ __align__(16) float4 wpackL[H];     // {Wd, Wc0, Wc1, Wc2}
  __shared__ float WcSH[SHD * 3];
  __shared__ float sc_a[T], sc_b[T];
  __shared__ float wred[4][4];

  short* Bs = (short*)BsP;
  float4* P4 = (float4*)BsP;

  // ---- stage weights ----
  {
    const float4* src = (const float4*)w2t;
    float4* dst = (float4*)BsP;
    #pragma unroll
    for (int i = 0; i < 8; ++i) dst[tid + i * 256] = src[tid + i * 256];
  }
  if (tid < 128) {
    wpackL[tid] = wpack[tid];
    b1s[tid] = b1[tid];
    b2s[tid] = b2[tid];
  }
  for (int i = tid; i < 3 * H; i += 256) W1s[i] = W1[i];
  if (tid < SHD * 3) WcSH[tid] = Wc[H * 3 + tid];

  // ---- per-ray setup ----
  const float ox = origins[ray*3+0], oy = origins[ray*3+1], oz = origins[ray*3+2];
  const float dx = dirs[ray*3+0],  dy = dirs[ray*3+1],  dz = dirs[ray*3+2];
  const float ix = 1.f/dx, iy = 1.f/dy, iz = 1.f/dz;
  const float t1x = (-1.f-ox)*ix, t2x = (1.f-ox)*ix;
  const float t1y = (-1.f-oy)*iy, t2y = (1.f-oy)*iy;
  const float t1z = (-1.f-oz)*iz, t2z = (1.f-oz)*iz;
  float tnear = fmaxf(fmaxf(fminf(t1x,t2x), fminf(t1y,t2y)), fminf(t1z,t2z));
  tnear = fmaxf(tnear, 0.f);
  const float tfar = fminf(fminf(fmaxf(t1x,t2x), fmaxf(t1y,t2y)), fmaxf(t1z,t2z));
  const bool  active = tfar > tnear;
  const float tfar_c = fmaxf(tfar, tnear + 1e-3f);
  const float dnorm = sqrtf(dx*dx + dy*dy + dz*dz);
  const float bd0 = bd[0];
  const float bc0 = bc[0], bc1 = bc[1], bc2 = bc[2];

  // ---- spherical harmonics ----
  float ynm[16];
  {
    const float nx = dx/dnorm, ny = dy/dnorm, nz = dz/dnorm;
    const float x2 = nx*nx, y2 = ny*ny, z2 = nz*nz;
    const float xy = nx*ny, yz = ny*nz, xz = nx*nz;
    ynm[0]  = 0.282094791773878f;
    ynm[1]  = -0.48860251190292f*ny;
    ynm[2]  = 0.48860251190292f*nz;
    ynm[3]  = -0.48860251190292f*nx;
    ynm[4]  = 1.0925484305920792f*xy;
    ynm[5]  = -1.0925484305920792f*yz;
    ynm[6]  = 0.94617469575756f*z2 - 0.31539156525252f;
    ynm[7]  = -1.0925484305920792f*xz;
    ynm[8]  = 0.5462742152960396f*(x2-y2);
    ynm[9]  = 0.5900435899266435f*ny*(-3.f*x2+y2);
    ynm[10] = 2.8906114426405538f*xy*nz;
    ynm[11] = 0.4570457994644658f*ny*(1.f-5.f*z2);
    ynm[12] = 0.3731763325901154f*nz*(5.f*z2-3.f);
    ynm[13] = 0.4570457994644658f*nx*(1.f-5.f*z2);
    ynm[14] = 1.445305721320277f*nz*(x2-y2);
    ynm[15] = 0.5900435899266435f*nx*(-x2+3.f*y2);
  }

  // ---- stratified samples ----
  if (tid < T) {
    const float ut = u[ray*T + tid];
    const float frac = ((float)tid + ut) * (1.f/(float)T);
    const float tt = tnear + (tfar_c - tnear) * frac;
    const float px = fmaf(dx, tt, ox);
    const float py = fmaf(dy, tt, oy);
    const float pz = fmaf(dz, tt, oz);
    xs4[tid] = make_float4(px, py, pz, tt);
    const bool m = (fabsf(px) <= 1.f) && (fabsf(py) <= 1.f) && (fabsf(pz) <= 1.f) && active;
    mask_s[tid] = m ? 1.f : 0.f;
  }
  __syncthreads();

  // ---- fused layer1 (VALU) + layer2 (MFMA) ----
  const float4 xa = xs4[32*w + c];        // row tm=0
  const float4 xb = xs4[32*w + 16 + c];   // row tm=1
  f32x4 acc[2][8];
  #pragma unroll
  for (int tm = 0; tm < 2; ++tm)
    #pragma unroll
    for (int nt = 0; nt < 8; ++nt)
      #pragma unroll
      for (int r = 0; r < 4; ++r) acc[tm][nt][r] = 0.f;

  #pragma unroll
  for (int ks = 0; ks < 4; ++ks) {
    const int kb = ks*32 + g*8;
    const float4 wxa = *(const float4*)&W1s[kb];
    const float4 wxb = *(const float4*)&W1s[kb+4];
    const float4 wya = *(const float4*)&W1s[128+kb];
    const float4 wyb = *(const float4*)&W1s[128+kb+4];
    const float4 wza = *(const float4*)&W1s[256+kb];
    const float4 wzb = *(const float4*)&W1s[256+kb+4];
    const float4 bba = *(const float4*)&b1s[kb];
    const float4 bbb = *(const float4*)&b1s[kb+4];
    const float wxv[8] = {wxa.x,wxa.y,wxa.z,wxa.w,wxb.x,wxb.y,wxb.z,wxb.w};
    const float wyv[8] = {wya.x,wya.y,wya.z,wya.w,wyb.x,wyb.y,wyb.z,wyb.w};
    const float wzv[8] = {wza.x,wza.y,wza.z,wza.w,wzb.x,wzb.y,wzb.z,wzb.w};
    const float bbv[8] = {bba.x,bba.y,bba.z,bba.w,bbb.x,bbb.y,bbb.z,bbb.w};
    short8 a0, a1;
    #pragma unroll
    for (int j = 0; j < 8; ++j) {
      const float v0 = fmaf(xa.x, wxv[j], fmaf(xa.y, wyv[j], fmaf(xa.z, wzv[j], bbv[j])));
      const float v1 = fmaf(xb.x, wxv[j], fmaf(xb.y, wyv[j], fmaf(xb.z, wzv[j], bbv[j])));
      a0[j] = (short)f2bf(fmaxf(v0, 0.f));
      a1[j] = (short)f2bf(fmaxf(v1, 0.f));
    }
    const int swb = ((ks*4 + g) ^ (c & 7)) * 8;  // swizzled octet byte-pos (in bf16 units)
    #pragma unroll
    for (int nt = 0; nt < 8; ++nt) {
      const short8 bf = *(const short8*)&Bs[(nt*16 + c)*128 + swb];
      acc[0][nt] = __builtin_amdgcn_mfma_f32_16x16x32_bf16(a0, bf, acc[0][nt], 0, 0, 0);
      acc[1][nt] = __builtin_amdgcn_mfma_f32_16x16x32_bf16(a1, bf, acc[1][nt], 0, 0, 0);
    }
  }

  // ---- epilogue partial dots (C-layout: row = g*4+reg, col = nt*16+c) ----
  float part[8][4];
  #pragma unroll
  for (int r = 0; r < 8; ++r)
    #pragma unroll
    for (int q = 0; q < 4; ++q) part[r][q] = 0.f;

  #pragma unroll
  for (int nt = 0; nt < 8; ++nt) {
    const int j = nt*16 + c;
    const float b2v = b2s[j];
    const float4 wp = wpackL[j];
    #pragma unroll
    for (int tm = 0; tm < 2; ++tm)
      #pragma unroll
      for (int r = 0; r < 4; ++r) {
        const float h2 = fmaxf(acc[tm][nt][r] + b2v, 0.f);
        float* pr = part[tm*4 + r];
        pr[0] = fmaf(h2, wp.x, pr[0]);
        pr[1] = fmaf(h2, wp.y, pr[1]);
        pr[2] = fmaf(h2, wp.z, pr[2]);
        pr[3] = fmaf(h2, wp.w, pr[3]);
      }
  }
  __syncthreads();   // all Bs reads done -> safe to overwrite with P
  #pragma unroll
  for (int r = 0; r < 8; ++r) {
    const int m = 32*w + (r >> 2)*16 + g*4 + (r & 3);
    P4[m*17 + c] = make_float4(part[r][0], part[r][1], part[r][2], part[r][3]);
  }
  __syncthreads();

  // ---- per-sample: reduce 16 partials + activations + transmittance terms ----
  float sd = 0.f, cc0 = 0.f, cc1 = 0.f, cc2 = 0.f;
  if (tid < T) {
    float Sx = 0.f, Sy = 0.f, Sz = 0.f, Sw = 0.f;
    #pragma unroll
    for (int p = 0; p < 16; ++p) {
      const float4 v = P4[tid*17 + p];
      Sx += v.x; Sy += v.y; Sz += v.z; Sw += v.w;
    }
    const float sigma = softplus_f(Sx + bd0) * mask_s[tid];
    float cp0 = Sy + bc0, cp1 = Sz + bc1, cp2 = Sw + bc2;
    #pragma unroll
    for (int s = 0; s < SHD; ++s) {
      cp0 = fmaf(ynm[s], WcSH[s*3+0], cp0);
      cp1 = fmaf(ynm[s], WcSH[s*3+1], cp1);
      cp2 = fmaf(ynm[s], WcSH[s*3+2], cp2);
    }
    const float m = mask_s[tid];
    cc0 = m / (1.f + expf(-cp0));
    cc1 = m / (1.f + expf(-cp1));
    cc2 = m / (1.f + expf(-cp2));
    const float tnext = (tid < T-1) ? xs4[tid+1].w : tfar_c * 10.f;
    const float delta = tnext - xs4[tid].w;
    sd = sigma * delta * dnorm;
    sc_a[tid] = sd;
  }
  __syncthreads();

  // ---- inclusive scan (Hillis-Steele) ----
  float* srcp = sc_a; float* dstp = sc_b;
  for (int off = 1; off < T; off <<= 1) {
    float v = 0.f;
    if (tid < T) { v = srcp[tid]; if (tid >= off) v += srcp[tid - off]; }
    __syncthreads();
    if (tid < T) dstp[tid] = v;
    __syncthreads();
    float* tmp = srcp; srcp = dstp; dstp = tmp;
  }

  // ---- weights + final reduction ----
  float wgt = 0.f, wc0 = 0.f, wc1 = 0.f, wc2 = 0.f;
  if (tid < T) {
    const float csum = srcp[tid];
    wgt = expf(sd - csum) - expf(-csum);
    wc0 = wgt * cc0; wc1 = wgt * cc1; wc2 = wgt * cc2;
  }
  #pragma unroll
  for (int m = 32; m >= 1; m >>= 1) {
    wgt += __shfl_xor(wgt, m);
    wc0 += __shfl_xor(wc0, m);
    wc1 += __shfl_xor(wc1, m);
    wc2 += __shfl_xor(wc2, m);
  }
  if ((tid & 63) == 0) {
    wred[tid>>6][0] = wgt; wred[tid>>6][1] = wc0;
    wred[tid>>6][2] = wc1; wred[tid>>6][3] = wc2;
  }
  __syncthreads();
  if (tid == 0) {
    float aw = 0.f, o0 = 0.f, o1 = 0.f, o2 = 0.f;
    #pragma unroll
    for (int i = 0; i < 4; ++i) {
      aw += wred[i][0]; o0 += wred[i][1]; o1 += wred[i][2]; o2 += wred[i][3];
    }
    out[ray*4+0] = active ? o0 : 0.f;
    out[ray*4+1] = active ? o1 : 0.f;
    out[ray*4+2] = active ? o2 : 0.f;
    out[ray*4+3] = active ? aw : 0.f;
  }
}

extern "C" void kernel_launch(void* const* d_in, const int* in_sizes, int n_in,
                              void* d_out, int out_size, void* d_ws, size_t ws_size,
                              hipStream_t stream) {
  const float* origins = (const float*)d_in[0];
  const float* dirs    = (const float*)d_in[1];
  const float* u       = (const float*)d_in[2];
  const float* W1      = (const float*)d_in[3];
  const float* b1      = (const float*)d_in[4];
  const float* W2      = (const float*)d_in[5];
  const float* b2      = (const float*)d_in[6];
  const float* Wd      = (const float*)d_in[7];
  const float* bd      = (const float*)d_in[8];
  const float* Wc      = (const float*)d_in[9];
  const float* bc      = (const float*)d_in[10];

  unsigned short* w2t = (unsigned short*)d_ws;
  float4* wpack = (float4*)((char*)d_ws + 32768);

  preprocess<<<64, 256, 0, stream>>>(W2, Wd, Wc, w2t, wpack);
  nerf_render<<<NRAYS, 256, 0, stream>>>(origins, dirs, u, W1, b1, b2, bd, Wc, bc,
                                         w2t, wpack, (float*)d_out);
}

// Round 3
// 161.179 us; speedup vs baseline: 3.1059x; 1.2068x over previous
//
#include <hip/hip_runtime.h>
#include <math.h>

#define NRAYS 8192
#define T 128
#define H 128
#define SHD 16
#define RPB 2
#define NBLK (NRAYS / RPB)

using short8 = __attribute__((ext_vector_type(8))) short;
using f32x4  = __attribute__((ext_vector_type(4))) float;

__device__ __forceinline__ float softplus_f(float x) {
  return fmaxf(x, 0.f) + log1pf(expf(-fabsf(x)));
}

// RNE float->bf16 (finite inputs)
__device__ __forceinline__ unsigned f2bf(float f) {
  unsigned u = __float_as_uint(f);
  return (u + 0x7fffu + ((u >> 16) & 1u)) >> 16;
}

// ---- preprocess ----
// w2t[n*128 + p]: p-octet o = (p>>3)^(n&7): holds W2[o*8+(p&7)][n]  (bf16, swizzled W2^T)
// woutf[(kk*64+L)*8+j]: A-frag for epilogue MFMA: A[m=c][k=kk*32+g*8+j],
//   rows: m=0 -> Wd, m=1..3 -> Wc[:,m-1], m>=4 -> 0   (L = g*16+c)
__global__ void preprocess(const float* __restrict__ W2, const float* __restrict__ Wd,
                           const float* __restrict__ Wc,
                           unsigned short* __restrict__ w2t,
                           unsigned short* __restrict__ woutf) {
  const int t = blockIdx.x * 256 + threadIdx.x;
  if (t < 16384) {
    const int n = t >> 7, p = t & 127;
    const int o = (p >> 3) ^ (n & 7);
    const int k = o * 8 + (p & 7);
    w2t[t] = (unsigned short)f2bf(W2[k * 128 + n]);
  }
  if (t < 2048) {
    const int kk = t >> 9, L = (t >> 3) & 63, j = t & 7;
    const int c = L & 15, g = L >> 4;
    const int k = kk * 32 + g * 8 + j;
    float v = 0.f;
    if (c == 0) v = Wd[k];
    else if (c < 4) v = Wc[k * 3 + (c - 1)];
    woutf[t] = (unsigned short)f2bf(v);
  }
}

__global__ __launch_bounds__(256, 2) void nerf_render(
    const float* __restrict__ origins, const float* __restrict__ dirs,
    const float* __restrict__ u, const float* __restrict__ W1,
    const float* __restrict__ b1, const float* __restrict__ b2,
    const float* __restrict__ bd, const float* __restrict__ Wc,
    const float* __restrict__ bc, const unsigned short* __restrict__ w2t,
    const unsigned short* __restrict__ woutf, float* __restrict__ out)
{
  const int ray0 = blockIdx.x * RPB;
  const int tid = threadIdx.x;
  const int L = tid & 63;
  const int w = tid >> 6;          // wave: samples [64w, 64w+64), ray = w>>1
  const int g = L >> 4;            // quad
  const int c = L & 15;

  __shared__ __align__(16) short Bs[16384];       // swizzled W2^T bf16 (A-operand); head reused as Sred
  __shared__ __align__(16) short Wouts[2048];     // epilogue A-frags
  __shared__ __align__(16) short As2[4 * 640];    // per-wave H2relu^T slab [16][40]
  __shared__ __align__(16) float4 xs4[RPB * T];   // {x,y,z,t}
  __shared__ float mask_s[RPB * T];
  __shared__ __align__(16) float W1s[3 * H];
  __shared__ __align__(16) float b1s[H];
  __shared__ __align__(16) float b2s[H];
  __shared__ float sc_a[RPB * T], sc_b[RPB * T];
  __shared__ float wred[4][4];
  __shared__ float rayp[RPB][4];                  // {tfar_c, dnorm, active, -}

  // ---- stage weights ----
  {
    const float4* src = (const float4*)w2t;
    float4* dst = (float4*)Bs;
    #pragma unroll
    for (int i = 0; i < 8; ++i) dst[tid + i * 256] = src[tid + i * 256];
    ((float4*)Wouts)[tid] = ((const float4*)woutf)[tid];
  }
  if (tid < H) { b1s[tid] = b1[tid]; b2s[tid] = b2[tid]; }
  for (int i = tid; i < 3 * H; i += 256) W1s[i] = W1[i];

  // ---- per-sample setup: tid <-> sample, ray = tid>>7 ----
  {
    const int r = tid >> 7, tl = tid & 127;
    const int gr = ray0 + r;
    const float ox = origins[gr*3+0], oy = origins[gr*3+1], oz = origins[gr*3+2];
    const float dx = dirs[gr*3+0],  dy = dirs[gr*3+1],  dz = dirs[gr*3+2];
    const float ix = 1.f/dx, iy = 1.f/dy, iz = 1.f/dz;
    const float t1x = (-1.f-ox)*ix, t2x = (1.f-ox)*ix;
    const float t1y = (-1.f-oy)*iy, t2y = (1.f-oy)*iy;
    const float t1z = (-1.f-oz)*iz, t2z = (1.f-oz)*iz;
    float tnear = fmaxf(fmaxf(fminf(t1x,t2x), fminf(t1y,t2y)), fminf(t1z,t2z));
    tnear = fmaxf(tnear, 0.f);
    const float tfar = fminf(fminf(fmaxf(t1x,t2x), fmaxf(t1y,t2y)), fmaxf(t1z,t2z));
    const bool  active = tfar > tnear;
    const float tfar_c = fmaxf(tfar, tnear + 1e-3f);
    const float ut = u[gr*T + tl];
    const float frac = ((float)tl + ut) * (1.f/(float)T);
    const float tt = tnear + (tfar_c - tnear) * frac;
    const float px = fmaf(dx, tt, ox);
    const float py = fmaf(dy, tt, oy);
    const float pz = fmaf(dz, tt, oz);
    xs4[tid] = make_float4(px, py, pz, tt);
    const bool m = (fabsf(px) <= 1.f) && (fabsf(py) <= 1.f) && (fabsf(pz) <= 1.f) && active;
    mask_s[tid] = m ? 1.f : 0.f;
    if (tl == 0) {
      rayp[r][0] = tfar_c;
      rayp[r][1] = sqrtf(dx*dx + dy*dy + dz*dz);
      rayp[r][2] = active ? 1.f : 0.f;
    }
  }
  __syncthreads();

  // ---- fused layer1 (VALU, in-register B-operand) + transposed layer2 (MFMA) ----
  // acc[tm][mt]: D[m=hidden2-in-tile = g*4+r (tile mt)][n=sample = 64w+16tm+c]
  f32x4 acc[4][8];
  #pragma unroll
  for (int tm = 0; tm < 4; ++tm)
    #pragma unroll
    for (int mt = 0; mt < 8; ++mt)
      #pragma unroll
      for (int r = 0; r < 4; ++r) acc[tm][mt][r] = 0.f;

  const float4 xv0 = xs4[64*w + c];
  const float4 xv1 = xs4[64*w + 16 + c];
  const float4 xv2 = xs4[64*w + 32 + c];
  const float4 xv3 = xs4[64*w + 48 + c];

  #pragma unroll
  for (int ks = 0; ks < 4; ++ks) {
    const int kb = ks*32 + g*8;
    const float4 wxa = *(const float4*)&W1s[kb];
    const float4 wxb = *(const float4*)&W1s[kb+4];
    const float4 wya = *(const float4*)&W1s[128+kb];
    const float4 wyb = *(const float4*)&W1s[128+kb+4];
    const float4 wza = *(const float4*)&W1s[256+kb];
    const float4 wzb = *(const float4*)&W1s[256+kb+4];
    const float4 bba = *(const float4*)&b1s[kb];
    const float4 bbb = *(const float4*)&b1s[kb+4];
    const float wxv[8] = {wxa.x,wxa.y,wxa.z,wxa.w,wxb.x,wxb.y,wxb.z,wxb.w};
    const float wyv[8] = {wya.x,wya.y,wya.z,wya.w,wyb.x,wyb.y,wyb.z,wyb.w};
    const float wzv[8] = {wza.x,wza.y,wza.z,wza.w,wzb.x,wzb.y,wzb.z,wzb.w};
    const float bbv[8] = {bba.x,bba.y,bba.z,bba.w,bbb.x,bbb.y,bbb.z,bbb.w};
    short8 af0, af1, af2, af3;   // B-frag: H1^T[k=g*8+j][sample=c]  per tm
    #pragma unroll
    for (int j = 0; j < 8; ++j) {
      const float wx = wxv[j], wy = wyv[j], wz = wzv[j], bb = bbv[j];
      const float v0 = fmaf(xv0.x, wx, fmaf(xv0.y, wy, fmaf(xv0.z, wz, bb)));
      const float v1 = fmaf(xv1.x, wx, fmaf(xv1.y, wy, fmaf(xv1.z, wz, bb)));
      const float v2 = fmaf(xv2.x, wx, fmaf(xv2.y, wy, fmaf(xv2.z, wz, bb)));
      const float v3 = fmaf(xv3.x, wx, fmaf(xv3.y, wy, fmaf(xv3.z, wz, bb)));
      af0[j] = (short)f2bf(fmaxf(v0, 0.f));
      af1[j] = (short)f2bf(fmaxf(v1, 0.f));
      af2[j] = (short)f2bf(fmaxf(v2, 0.f));
      af3[j] = (short)f2bf(fmaxf(v3, 0.f));
    }
    const int swb = ((ks*4 + g) ^ (c & 7)) * 8;
    #pragma unroll
    for (int mt = 0; mt < 8; ++mt) {
      // A-frag: W2^T[m=hidden2=mt*16+c][k=ks*32+g*8+j]
      const short8 wf = *(const short8*)&Bs[(mt*16 + c)*128 + swb];
      acc[0][mt] = __builtin_amdgcn_mfma_f32_16x16x32_bf16(wf, af0, acc[0][mt], 0, 0, 0);
      acc[1][mt] = __builtin_amdgcn_mfma_f32_16x16x32_bf16(wf, af1, acc[1][mt], 0, 0, 0);
      acc[2][mt] = __builtin_amdgcn_mfma_f32_16x16x32_bf16(wf, af2, acc[2][mt], 0, 0, 0);
      acc[3][mt] = __builtin_amdgcn_mfma_f32_16x16x32_bf16(wf, af3, acc[3][mt], 0, 0, 0);
    }
  }

  __syncthreads();   // all waves done reading Bs -> safe to alias Sred onto it
  float4* SredP = (float4*)Bs;   // [256] float4 {sigma_pre, cp0, cp1, cp2}

  // ---- epilogue: b2+relu -> bf16 slab -> 4-k-step MFMA dot with Wout ----
  short* As2w = As2 + w * 640;   // per-wave slab [16 samples][40] bf16 (32 used + pad)
  short8 wa[4];
  #pragma unroll
  for (int kk = 0; kk < 4; ++kk) wa[kk] = *(const short8*)&Wouts[(kk*64 + L)*8];

  #pragma unroll
  for (int tm = 0; tm < 4; ++tm) {
    f32x4 oacc;
    oacc[0] = 0.f; oacc[1] = 0.f; oacc[2] = 0.f; oacc[3] = 0.f;
    #pragma unroll
    for (int kk = 0; kk < 4; ++kk) {
      #pragma unroll
      for (int i = 0; i < 2; ++i) {
        const int mt = kk*2 + i;
        const float4 bv = *(const float4*)&b2s[mt*16 + g*4];
        const f32x4 a = acc[tm][mt];
        const float h0 = fmaxf(a[0] + bv.x, 0.f);
        const float h1 = fmaxf(a[1] + bv.y, 0.f);
        const float h2 = fmaxf(a[2] + bv.z, 0.f);
        const float h3 = fmaxf(a[3] + bv.w, 0.f);
        const unsigned p01 = f2bf(h0) | (f2bf(h1) << 16);
        const unsigned p23 = f2bf(h2) | (f2bf(h3) << 16);
        *(uint2*)&As2w[c*40 + i*16 + g*4] = make_uint2(p01, p23);
      }
      const short8 hb = *(const short8*)&As2w[c*40 + g*8];
      oacc = __builtin_amdgcn_mfma_f32_16x16x32_bf16(wa[kk], hb, oacc, 0, 0, 0);
    }
    if (g == 0)   // lane holds outputs m=0..3 for sample 64w+16tm+c
      SredP[64*w + 16*tm + c] = make_float4(oacc[0], oacc[1], oacc[2], oacc[3]);
  }
  __syncthreads();

  // ---- per-sample activations + transmittance ----
  const int r2 = tid >> 7, tl2 = tid & 127;
  const int gr2 = ray0 + r2;
  const float tfar_c2 = rayp[r2][0];
  const float dnorm2  = rayp[r2][1];
  const float4 sv = SredP[tid];
  const float mk = mask_s[tid];
  const float sigma = softplus_f(sv.x + bd[0]) * mk;
  float cc0, cc1, cc2;
  {
    const float dxr = dirs[gr2*3+0], dyr = dirs[gr2*3+1], dzr = dirs[gr2*3+2];
    const float nx = dxr/dnorm2, ny = dyr/dnorm2, nz = dzr/dnorm2;
    const float x2 = nx*nx, y2 = ny*ny, z2 = nz*nz;
    const float xy = nx*ny, yz = ny*nz, xz = nx*nz;
    float ynm[16];
    ynm[0]  = 0.282094791773878f;
    ynm[1]  = -0.48860251190292f*ny;
    ynm[2]  = 0.48860251190292f*nz;
    ynm[3]  = -0.48860251190292f*nx;
    ynm[4]  = 1.0925484305920792f*xy;
    ynm[5]  = -1.0925484305920792f*yz;
    ynm[6]  = 0.94617469575756f*z2 - 0.31539156525252f;
    ynm[7]  = -1.0925484305920792f*xz;
    ynm[8]  = 0.5462742152960396f*(x2-y2);
    ynm[9]  = 0.5900435899266435f*ny*(-3.f*x2+y2);
    ynm[10] = 2.8906114426405538f*xy*nz;
    ynm[11] = 0.4570457994644658f*ny*(1.f-5.f*z2);
    ynm[12] = 0.3731763325901154f*nz*(5.f*z2-3.f);
    ynm[13] = 0.4570457994644658f*nx*(1.f-5.f*z2);
    ynm[14] = 1.445305721320277f*nz*(x2-y2);
    ynm[15] = 0.5900435899266435f*nx*(-x2+3.f*y2);
    float cp0 = sv.y + bc[0], cp1 = sv.z + bc[1], cp2 = sv.w + bc[2];
    #pragma unroll
    for (int s = 0; s < SHD; ++s) {
      cp0 = fmaf(ynm[s], Wc[(H+s)*3+0], cp0);
      cp1 = fmaf(ynm[s], Wc[(H+s)*3+1], cp1);
      cp2 = fmaf(ynm[s], Wc[(H+s)*3+2], cp2);
    }
    cc0 = mk / (1.f + expf(-cp0));
    cc1 = mk / (1.f + expf(-cp1));
    cc2 = mk / (1.f + expf(-cp2));
  }
  const float tnext = (tl2 < T-1) ? xs4[tid+1].w : tfar_c2 * 10.f;
  const float sd = sigma * (tnext - xs4[tid].w) * dnorm2;
  sc_a[tid] = sd;
  __syncthreads();

  // ---- segmented inclusive scan (2 rays in parallel) ----
  float* srcp = sc_a; float* dstp = sc_b;
  for (int off = 1; off < T; off <<= 1) {
    float v = srcp[tid];
    if (tl2 >= off) v += srcp[tid - off];
    __syncthreads();
    dstp[tid] = v;
    __syncthreads();
    float* tp = srcp; srcp = dstp; dstp = tp;
  }

  // ---- weights + per-ray reduction (wave w belongs entirely to ray w>>1) ----
  const float csum = srcp[tid];
  float wgt = expf(sd - csum) - expf(-csum);
  float wcx = wgt * cc0, wcy = wgt * cc1, wcz = wgt * cc2;
  #pragma unroll
  for (int mm = 32; mm >= 1; mm >>= 1) {
    wgt += __shfl_xor(wgt, mm);
    wcx += __shfl_xor(wcx, mm);
    wcy += __shfl_xor(wcy, mm);
    wcz += __shfl_xor(wcz, mm);
  }
  if (L == 0) { wred[w][0] = wgt; wred[w][1] = wcx; wred[w][2] = wcy; wred[w][3] = wcz; }
  __syncthreads();
  if (tid < RPB) {
    const int rr = tid;
    const float aw = wred[2*rr][0] + wred[2*rr+1][0];
    const float o0 = wred[2*rr][1] + wred[2*rr+1][1];
    const float o1 = wred[2*rr][2] + wred[2*rr+1][2];
    const float o2 = wred[2*rr][3] + wred[2*rr+1][3];
    const bool act = rayp[rr][2] != 0.f;
    out[(ray0+rr)*4+0] = act ? o0 : 0.f;
    out[(ray0+rr)*4+1] = act ? o1 : 0.f;
    out[(ray0+rr)*4+2] = act ? o2 : 0.f;
    out[(ray0+rr)*4+3] = act ? aw : 0.f;
  }
}

extern "C" void kernel_launch(void* const* d_in, const int* in_sizes, int n_in,
                              void* d_out, int out_size, void* d_ws, size_t ws_size,
                              hipStream_t stream) {
  const float* origins = (const float*)d_in[0];
  const float* dirs    = (const float*)d_in[1];
  const float* u       = (const float*)d_in[2];
  const float* W1      = (const float*)d_in[3];
  const float* b1      = (const float*)d_in[4];
  const float* W2      = (const float*)d_in[5];
  const float* b2      = (const float*)d_in[6];
  const float* Wd      = (const float*)d_in[7];
  const float* bd      = (const float*)d_in[8];
  const float* Wc      = (const float*)d_in[9];
  const float* bc      = (const float*)d_in[10];

  unsigned short* w2t   = (unsigned short*)d_ws;
  unsigned short* woutf = (unsigned short*)((char*)d_ws + 32768);

  preprocess<<<64, 256, 0, stream>>>(W2, Wd, Wc, w2t, woutf);
  nerf_render<<<NBLK, 256, 0, stream>>>(origins, dirs, u, W1, b1, b2, bd, Wc, bc,
                                        w2t, woutf, (float*)d_out);
}